// Round 2
// baseline (348.207 us; speedup 1.0000x reference)
//
#include <hip/hip_runtime.h>

// ---------------- shared constants ----------------
#define HW_SZ   (1024*1024)
#define NPIX    16777216.0        // 16*1024*1024
#define GROUPS  (16*1024*1024/4)  // 4 pixels per packed byte
#define PAIRS   (GROUPS/2)        // 2 groups (8 px) per thread-iter

// edge_pack tiling
#define TW   128
#define TH   32
#define HALO 5
#define TIW  (TW + 2*HALO)   // 138
#define TIH  (TH + 2*HALO)   // 42
#define TB_P 144
#define VS_P 142
#define NBX  8
#define NBY  32
#define NBZ  16
#define NB1  (NBX*NBY*NBZ)   // 4096

#define NB2  2048            // loss_stream blocks

// ws layout (split path):
//   [0, 4MiB)                       packed bytes (e,t 2 bits/px, 4 px/byte)
//   [4MiB, 4MiB+16KB)               cnt partials, NB1 floats
//   [4MiB+16KB, +4*NB2*4)           score partials [4][NB2]
#define PACKED_BYTES (GROUPS)
#define WS_NEEDED (PACKED_BYTES + NB1*4 + 4*NB2*4)

// ================= split path: kernel 1 =================
// Edge mask from target only; writes packed (t,e) bits + per-block edge count.
__global__ __launch_bounds__(256)
void edge_pack(const int* __restrict__ target,
               unsigned char* __restrict__ packed,
               float* __restrict__ cntpart) {
    __shared__ unsigned char  tb[TIH][TB_P];
    __shared__ unsigned short vs[TH][VS_P];
    __shared__ float          red[4];

    const int tid   = threadIdx.x;
    const int tileX = blockIdx.x * TW;
    const int tileY = blockIdx.y * TH;
    const int b     = blockIdx.z;
    const int bid   = (blockIdx.z * NBY + blockIdx.y) * NBX + blockIdx.x;

    const int* tgt = target + (size_t)b * HW_SZ;

    // stage target tile + halo (zeros outside)
    for (int idx = tid; idx < TIH * TIW; idx += 256) {
        int rr = idx / TIW;
        int cc = idx - rr * TIW;
        int gr = tileY + rr - HALO;
        int gc = tileX + cc - HALO;
        unsigned char v = 0;
        if ((unsigned)gr < 1024u && (unsigned)gc < 1024u)
            v = (unsigned char)tgt[gr * 1024 + gc];
        tb[rr][cc] = v;
    }
    __syncthreads();

    // vertical sliding column sums (window 11)
    if (tid < TIW) {
        int acc = 0;
        #pragma unroll
        for (int rr = 0; rr < 11; ++rr) acc += tb[rr][tid];
        vs[0][tid] = (unsigned short)acc;
        for (int r = 1; r < TH; ++r) {
            acc += (int)tb[r + 10][tid] - (int)tb[r - 1][tid];
            vs[r][tid] = (unsigned short)acc;
        }
    }
    __syncthreads();

    const int tx = tid & 31;   // 32 groups of 4 cols = 128
    const int ty = tid >> 5;   // 8 rows/pass, 4 passes

    int cnt = 0;
    #pragma unroll
    for (int p = 0; p < 4; ++p) {
        const int r  = ty + p * 8;
        const int gr = tileY + r;
        const int c0 = tx * 4;

        int S[4];
        int s = 0;
        #pragma unroll
        for (int k = 0; k < 11; ++k) s += vs[r][c0 + k];
        S[0] = s;
        #pragma unroll
        for (int j = 1; j < 4; ++j) {
            s += (int)vs[r][c0 + 10 + j] - (int)vs[r][c0 + j - 1];
            S[j] = s;
        }

        unsigned int pk = 0;
        #pragma unroll
        for (int j = 0; j < 4; ++j) {
            const int t = tb[r + 5][c0 + 5 + j];
            const int e = (S[j] != 121 * t) ? 1 : 0;
            cnt += e;
            pk |= (unsigned)(t << (2 * j)) | (unsigned)(e << (2 * j + 1));
        }
        packed[((size_t)b << 18) + (gr << 8) + (tileX >> 2) + tx] = (unsigned char)pk;
    }

    // reduce cnt
    float v = (float)cnt;
    #pragma unroll
    for (int off = 32; off > 0; off >>= 1) v += __shfl_down(v, off);
    const int lane = tid & 63, wv = tid >> 6;
    if (lane == 0) red[wv] = v;
    __syncthreads();
    if (tid == 0) cntpart[bid] = red[0] + red[1] + red[2] + red[3];
}

// ================= split path: kernel 2 =================
__device__ __forceinline__ void px_term(float p0, float p1, int t, float e,
                                        float& s1, float& s2) {
    float m   = fmaxf(p0, p1);
    float lse = m + __logf(1.0f + __expf(-fabsf(p0 - p1)));
    float lpt = (t ? p1 : p0) - lse;
    float slp = p0 + p1 - 2.0f * lse;
    s1 += lpt;
    s2 += e * (slp - 1.5f * lpt);
}

__global__ __launch_bounds__(256)
void loss_stream(const float* __restrict__ score0,
                 const float* __restrict__ score1,
                 const unsigned char* __restrict__ packed,
                 float* __restrict__ spart) {
    const int tid = threadIdx.x;
    const unsigned short* pk16 = (const unsigned short*)packed;

    float a1 = 0.f, a2 = 0.f, b1 = 0.f, b2 = 0.f;

    for (int pp = blockIdx.x * 256 + tid; pp < PAIRS; pp += NB2 * 256) {
        const int b = pp >> 17;                       // HW/8 pairs per image
        const size_t off = ((size_t)pp << 3) + ((size_t)b << 20);

        // 8 independent 16B loads (4 planes x 2 groups) — deep MLP
        float4 x0a = *(const float4*)(score0 + off);
        float4 x0b = *(const float4*)(score0 + off + 4);
        float4 x1a = *(const float4*)(score0 + off + HW_SZ);
        float4 x1b = *(const float4*)(score0 + off + HW_SZ + 4);
        float4 y0a = *(const float4*)(score1 + off);
        float4 y0b = *(const float4*)(score1 + off + 4);
        float4 y1a = *(const float4*)(score1 + off + HW_SZ);
        float4 y1b = *(const float4*)(score1 + off + HW_SZ + 4);
        const unsigned int pk = pk16[pp];

        float p0[8] = {x0a.x, x0a.y, x0a.z, x0a.w, x0b.x, x0b.y, x0b.z, x0b.w};
        float p1[8] = {x1a.x, x1a.y, x1a.z, x1a.w, x1b.x, x1b.y, x1b.z, x1b.w};
        float q0[8] = {y0a.x, y0a.y, y0a.z, y0a.w, y0b.x, y0b.y, y0b.z, y0b.w};
        float q1[8] = {y1a.x, y1a.y, y1a.z, y1a.w, y1b.x, y1b.y, y1b.z, y1b.w};

        #pragma unroll
        for (int j = 0; j < 8; ++j) {
            const int   t = (pk >> (2 * j)) & 1;
            const float e = (float)((pk >> (2 * j + 1)) & 1);
            px_term(p0[j], p1[j], t, e, a1, a2);
            px_term(q0[j], q1[j], t, e, b1, b2);
        }
    }

    __shared__ float red[4][4];
    float vals[4] = {a1, a2, b1, b2};
    const int lane = tid & 63, wv = tid >> 6;
    #pragma unroll
    for (int q = 0; q < 4; ++q) {
        float v = vals[q];
        #pragma unroll
        for (int off = 32; off > 0; off >>= 1) v += __shfl_down(v, off);
        if (lane == 0) red[wv][q] = v;
    }
    __syncthreads();
    if (tid == 0) {
        #pragma unroll
        for (int q = 0; q < 4; ++q)
            spart[q * NB2 + blockIdx.x] = red[0][q] + red[1][q] + red[2][q] + red[3][q];
    }
}

// ================= split path: finalize =================
__global__ __launch_bounds__(256)
void finalize2(const float* __restrict__ cntpart,
               const float* __restrict__ spart,
               float* __restrict__ out) {
    __shared__ double red[4][5];
    const int tid = threadIdx.x;
    double acc[5] = {0, 0, 0, 0, 0};
    for (int i = tid; i < NB1; i += 256) acc[0] += (double)cntpart[i];
    for (int i = tid; i < NB2; i += 256) {
        #pragma unroll
        for (int q = 0; q < 4; ++q) acc[q + 1] += (double)spart[q * NB2 + i];
    }
    const int lane = tid & 63, wv = tid >> 6;
    #pragma unroll
    for (int q = 0; q < 5; ++q) {
        double v = acc[q];
        #pragma unroll
        for (int off = 32; off > 0; off >>= 1) v += __shfl_down(v, off);
        if (lane == 0) red[wv][q] = v;
    }
    __syncthreads();
    if (tid == 0) {
        double s[5];
        #pragma unroll
        for (int q = 0; q < 5; ++q)
            s[q] = red[0][q] + red[1][q] + red[2][q] + red[3][q];
        double alpha = s[0] / NPIX;
        if (alpha > 0.2) alpha = 0.2;
        double loss = (s[1] + alpha * s[2]) + 0.5 * (s[3] + alpha * s[4]);
        out[0] = (float)(-loss / NPIX);
    }
}

// ================= fallback path (R1 fused) =================
__global__ __launch_bounds__(256)
void fused_edge_loss(const float* __restrict__ score0,
                     const float* __restrict__ score1,
                     const int*   __restrict__ target,
                     float*       __restrict__ ws) {
    __shared__ unsigned char  tb[TIH][TB_P];
    __shared__ unsigned short vs[TH][VS_P];
    __shared__ float          red[4][5];

    const int tid   = threadIdx.x;
    const int tileX = blockIdx.x * TW;
    const int tileY = blockIdx.y * TH;
    const int b     = blockIdx.z;
    const int bid   = (blockIdx.z * NBY + blockIdx.y) * NBX + blockIdx.x;

    const int* tgt = target + (size_t)b * HW_SZ;

    for (int idx = tid; idx < TIH * TIW; idx += 256) {
        int rr = idx / TIW;
        int cc = idx - rr * TIW;
        int gr = tileY + rr - HALO;
        int gc = tileX + cc - HALO;
        unsigned char v = 0;
        if ((unsigned)gr < 1024u && (unsigned)gc < 1024u)
            v = (unsigned char)tgt[gr * 1024 + gc];
        tb[rr][cc] = v;
    }
    __syncthreads();

    if (tid < TIW) {
        int acc = 0;
        #pragma unroll
        for (int rr = 0; rr < 11; ++rr) acc += tb[rr][tid];
        vs[0][tid] = (unsigned short)acc;
        for (int r = 1; r < TH; ++r) {
            acc += (int)tb[r + 10][tid] - (int)tb[r - 1][tid];
            vs[r][tid] = (unsigned short)acc;
        }
    }
    __syncthreads();

    const float* s0b = score0 + (size_t)b * (2 * HW_SZ);
    const float* s1b = score1 + (size_t)b * (2 * HW_SZ);
    const int tx = tid & 31;
    const int ty = tid >> 5;

    float cnt = 0.f, a1 = 0.f, a2 = 0.f, b1 = 0.f, b2 = 0.f;

    #pragma unroll
    for (int p = 0; p < 4; ++p) {
        const int r  = ty + p * 8;
        const int gr = tileY + r;
        const int c0 = tx * 4;
        const int gc = tileX + c0;

        int S[4];
        int s = 0;
        #pragma unroll
        for (int k = 0; k < 11; ++k) s += vs[r][c0 + k];
        S[0] = s;
        #pragma unroll
        for (int j = 1; j < 4; ++j) {
            s += (int)vs[r][c0 + 10 + j] - (int)vs[r][c0 + j - 1];
            S[j] = s;
        }

        const size_t base = (size_t)gr * 1024 + gc;
        float4 x0 = *(const float4*)(s0b + base);
        float4 x1 = *(const float4*)(s0b + HW_SZ + base);
        float4 y0 = *(const float4*)(s1b + base);
        float4 y1 = *(const float4*)(s1b + HW_SZ + base);
        float p0a[4] = {x0.x, x0.y, x0.z, x0.w};
        float p1a[4] = {x1.x, x1.y, x1.z, x1.w};
        float q0a[4] = {y0.x, y0.y, y0.z, y0.w};
        float q1a[4] = {y1.x, y1.y, y1.z, y1.w};

        #pragma unroll
        for (int j = 0; j < 4; ++j) {
            const int t = tb[r + 5][c0 + 5 + j];
            const float e = (S[j] != 121 * t) ? 1.0f : 0.0f;
            cnt += e;
            px_term(p0a[j], p1a[j], t, e, a1, a2);
            px_term(q0a[j], q1a[j], t, e, b1, b2);
        }
    }

    float vals[5] = {cnt, a1, a2, b1, b2};
    const int lane = tid & 63, wv = tid >> 6;
    #pragma unroll
    for (int q = 0; q < 5; ++q) {
        float v = vals[q];
        #pragma unroll
        for (int off = 32; off > 0; off >>= 1) v += __shfl_down(v, off);
        if (lane == 0) red[wv][q] = v;
    }
    __syncthreads();
    if (tid == 0) {
        #pragma unroll
        for (int q = 0; q < 5; ++q)
            ws[q * NB1 + bid] = red[0][q] + red[1][q] + red[2][q] + red[3][q];
    }
}

__global__ __launch_bounds__(256)
void finalize_loss(const float* __restrict__ ws, float* __restrict__ out) {
    __shared__ double red[4][5];
    const int tid = threadIdx.x;
    double acc[5] = {0, 0, 0, 0, 0};
    for (int i = tid; i < NB1; i += 256) {
        #pragma unroll
        for (int q = 0; q < 5; ++q) acc[q] += (double)ws[q * NB1 + i];
    }
    const int lane = tid & 63, wv = tid >> 6;
    #pragma unroll
    for (int q = 0; q < 5; ++q) {
        double v = acc[q];
        #pragma unroll
        for (int off = 32; off > 0; off >>= 1) v += __shfl_down(v, off);
        if (lane == 0) red[wv][q] = v;
    }
    __syncthreads();
    if (tid == 0) {
        double s[5];
        #pragma unroll
        for (int q = 0; q < 5; ++q)
            s[q] = red[0][q] + red[1][q] + red[2][q] + red[3][q];
        double alpha = s[0] / NPIX;
        if (alpha > 0.2) alpha = 0.2;
        double loss = (s[1] + alpha * s[2]) + 0.5 * (s[3] + alpha * s[4]);
        out[0] = (float)(-loss / NPIX);
    }
}

// ================= launch =================
extern "C" void kernel_launch(void* const* d_in, const int* in_sizes, int n_in,
                              void* d_out, int out_size, void* d_ws, size_t ws_size,
                              hipStream_t stream) {
    const float* score0 = (const float*)d_in[0];
    const float* score1 = (const float*)d_in[1];
    const int*   target = (const int*)d_in[2];
    float* out = (float*)d_out;

    if (ws_size >= (size_t)WS_NEEDED) {
        unsigned char* packed  = (unsigned char*)d_ws;
        float*         cntpart = (float*)((char*)d_ws + PACKED_BYTES);
        float*         spart   = cntpart + NB1;

        dim3 grid1(NBX, NBY, NBZ);
        edge_pack<<<grid1, 256, 0, stream>>>(target, packed, cntpart);
        loss_stream<<<NB2, 256, 0, stream>>>(score0, score1, packed, spart);
        finalize2<<<1, 256, 0, stream>>>(cntpart, spart, out);
    } else {
        float* ws = (float*)d_ws;  // 80 KB
        dim3 grid(NBX, NBY, NBZ);
        fused_edge_loss<<<grid, 256, 0, stream>>>(score0, score1, target, ws);
        finalize_loss<<<1, 256, 0, stream>>>(ws, out);
    }
}